// Round 6
// baseline (10714.606 us; speedup 1.0000x reference)
//
#include <hip/hip_runtime.h>
#include <hip/hip_bf16.h>

typedef __bf16 bf16x8 __attribute__((ext_vector_type(8)));
typedef float floatx4 __attribute__((ext_vector_type(4)));

#define HID 1024
#define HH (1024*1024)
#define SEQ 512
#define NB 32768  /* 32*1024 state elements */
#define NBLK 256

__device__ __forceinline__ float bf2f(unsigned short u) {
  union { unsigned int i; float f; } v; v.i = ((unsigned int)u) << 16; return v.f;
}
__device__ __forceinline__ unsigned short f2bf(float f) {
  union { float f; unsigned int i; } v; v.f = f;
  unsigned int i = v.i;
  return (unsigned short)((i + 0x7fffu + ((i >> 16) & 1u)) >> 16);
}
__device__ __forceinline__ float ldflag(const void* p, long i, int flag) {
  return flag ? ((const float*)p)[i] : bf2f(((const unsigned short*)p)[i]);
}
__device__ __forceinline__ float sigmoidf_(float x) { return 1.0f / (1.0f + __expf(-x)); }

// init-time stores (proven r3/r5 path; init barrier's wbl2 flushes them)
#define GSTH(p_, v_)   asm volatile("global_store_short %0, %1, off sc0 sc1" :: "v"(p_), "v"(v_) : "memory")
#define GSTW(p_, v_)   asm volatile("global_store_dword %0, %1, off sc0 sc1" :: "v"(p_), "v"(v_) : "memory")

// ---- fire-and-forget IF-coherent stores: agent-scope atomic swaps.
// Atomics are serviced memory-side at the Infinity Cache (proven by the
// barrier counters all session), so after vmcnt(0) the data is globally
// visible WITHOUT any release fence / buffer_wbl2. 16-bit data is packed in
// pairs (lane l and l^1) and issued by the even lane.
__device__ __forceinline__ void aswapF2(float* addr, float lo, float hi) {
  union { float f[2]; unsigned long long u; } p; p.f[0] = lo; p.f[1] = hi;
  __hip_atomic_exchange((unsigned long long*)addr, p.u,
                        __ATOMIC_RELAXED, __HIP_MEMORY_SCOPE_AGENT);
}
__device__ __forceinline__ void aswapH2(unsigned short* addr, unsigned lo, unsigned hi) {
  __hip_atomic_exchange((unsigned int*)addr, (lo & 0xffffu) | (hi << 16),
                        __ATOMIC_RELAXED, __HIP_MEMORY_SCOPE_AGENT);
}

// ---- dtype detection: bf16 (flag=0) vs fp32 (flag=1) ----
__global__ void detect_k(const unsigned int* __restrict__ xw, int* __restrict__ flag) {
  unsigned int w = xw[threadIdx.x];
  int e = (w >> 7) & 0xFF;
  int ok = (e >= 100 && e <= 141) ? 1 : 0;
  unsigned long long m = __ballot(ok);
  if (threadIdx.x == 0) *flag = (__popcll(m) >= 36) ? 0 : 1;
}

// ---- fp32 -> bf16 conversion of x, 6 weight tensors, WY (no-op when flag=0) ----
__global__ void convert_k(const float* __restrict__ x,
                          const float* __restrict__ w0, const float* __restrict__ w1,
                          const float* __restrict__ w2, const float* __restrict__ w3,
                          const float* __restrict__ w4, const float* __restrict__ w5,
                          const float* __restrict__ wy,
                          unsigned short* __restrict__ xb, unsigned short* __restrict__ wc,
                          unsigned short* __restrict__ wyc, const int* __restrict__ flag) {
  if (*flag == 0) return;
  const float* Ws[6] = { w0, w1, w2, w3, w4, w5 };
  const long total = 3801088;
  for (long c = (long)blockIdx.x * 256 + threadIdx.x; c < total; c += (long)gridDim.x * 256) {
    long e = c * 8;
    const float* src; unsigned short* dst; long off;
    if (e < 16777216)      { src = x;  dst = xb;  off = e; }
    else if (e < 29360128) { long r = e - 16777216; int wi = (int)(r >> 21);
                             src = Ws[wi]; dst = wc + (long)wi * 2097152; off = r & 2097151; }
    else                   { src = wy; dst = wyc; off = e - 29360128; }
    float4 a = *(const float4*)(src + off);
    float4 b = *(const float4*)(src + off + 4);
    uint4 o;
    o.x = (unsigned)f2bf(a.x) | ((unsigned)f2bf(a.y) << 16);
    o.y = (unsigned)f2bf(a.z) | ((unsigned)f2bf(a.w) << 16);
    o.z = (unsigned)f2bf(b.x) | ((unsigned)f2bf(b.y) << 16);
    o.w = (unsigned)f2bf(b.z) | ((unsigned)f2bf(b.w) << 16);
    *(uint4*)(dst + off) = o;
  }
}

// ---- init-time grid barrier: round-3 proven (full fences per block) ----
__device__ __forceinline__ void gbar(int* cnt, int target, int blk) {
  __syncthreads();
  if (threadIdx.x == 0) {
    __builtin_amdgcn_fence(__ATOMIC_RELEASE, "agent");
    __hip_atomic_fetch_add(cnt + (blk & 7) * 64, 1, __ATOMIC_RELAXED, __HIP_MEMORY_SCOPE_AGENT);
    int ssum;
    do {
      ssum = 0;
      #pragma unroll
      for (int i = 0; i < 8; ++i)
        ssum += __hip_atomic_load(cnt + i * 64, __ATOMIC_RELAXED, __HIP_MEMORY_SCOPE_AGENT);
      if (ssum < target) __builtin_amdgcn_s_sleep(1);
    } while (ssum < target);
    __builtin_amdgcn_fence(__ATOMIC_ACQUIRE, "agent");
  }
  __syncthreads();
}

// ---- per-phase barrier, leader-based, NO release fence.
// All phase-loop stores are IF-side atomic swaps drained by vmcnt(0), so
// nothing dirty sits in L2 (also why the acquire-inv can't discard data).
// Leader (fixed at init): waits local arrivals -> posts XCD total -> polls
// global -> acquire fence (L1+L2 inv) -> posts go. Members: 1 arrival RMW,
// poll go, own-CU L1 buffer_inv.
__device__ __forceinline__ void gbar3(int* xcdArr, int* gCnt, int* xcdGo,
                                      int myxcd, int xcdTot, int lead, int pidx) {
  asm volatile("s_waitcnt vmcnt(0)" ::: "memory");  // this wave's swaps acked at IF
  __syncthreads();                                  // all waves drained
  if (threadIdx.x == 0) {
    __hip_atomic_fetch_add(xcdArr + myxcd * 64, 1, __ATOMIC_RELAXED, __HIP_MEMORY_SCOPE_AGENT);
    if (lead) {
      while (__hip_atomic_load(xcdArr + myxcd * 64, __ATOMIC_RELAXED,
                               __HIP_MEMORY_SCOPE_AGENT) < pidx * xcdTot)
        __builtin_amdgcn_s_sleep(1);
      __hip_atomic_fetch_add(gCnt + myxcd * 64, xcdTot,
                             __ATOMIC_RELAXED, __HIP_MEMORY_SCOPE_AGENT);
      int ssum;
      do {
        ssum = 0;
        #pragma unroll
        for (int i = 0; i < 8; ++i)
          ssum += __hip_atomic_load(gCnt + i * 64, __ATOMIC_RELAXED, __HIP_MEMORY_SCOPE_AGENT);
        if (ssum < NBLK * pidx) __builtin_amdgcn_s_sleep(1);
      } while (ssum < NBLK * pidx);
      __builtin_amdgcn_fence(__ATOMIC_ACQUIRE, "agent");   // L1+L2 inv (this XCD)
      __hip_atomic_store(xcdGo + myxcd * 64, pidx,
                         __ATOMIC_RELAXED, __HIP_MEMORY_SCOPE_AGENT);
    } else {
      while (__hip_atomic_load(xcdGo + myxcd * 64, __ATOMIC_RELAXED,
                               __HIP_MEMORY_SCOPE_AGENT) < pidx)
        __builtin_amdgcn_s_sleep(1);
      asm volatile("buffer_inv" ::: "memory");             // own-CU L1 invalidate
    }
  }
  __syncthreads();
}

// ---- stage a (W,U) pair of 16 rows x K=1024 each into MFMA-frag-ordered LDS ----
__device__ __forceinline__ void stage2(unsigned short* dst,
                                       const unsigned short* __restrict__ s0,
                                       const unsigned short* __restrict__ s1,
                                       int n0, int tid) {
  const unsigned short* srcs[2] = { s0, s1 };
  #pragma unroll
  for (int i = 0; i < 16; ++i) {
    int idx = i * 256 + tid;
    int m = idx >> 11;
    int rem = idx & 2047;
    int r = rem >> 7, k8 = rem & 127;
    bf16x8 v = *(const bf16x8*)(srcs[m] + (long)(n0 + r) * HID + k8 * 8);
    int kc = k8 >> 2, L = ((k8 & 3) << 4) | r;
    *(bf16x8*)(dst + (((m * 32 + kc) * 64 + L) << 3)) = v;
  }
}
__device__ __forceinline__ void stage1(unsigned short* dst,
                                       const unsigned short* __restrict__ s0,
                                       int n0, int tid) {
  #pragma unroll
  for (int i = 0; i < 8; ++i) {
    int idx = i * 256 + tid;
    int r = idx >> 7, k8 = idx & 127;
    bf16x8 v = *(const bf16x8*)(s0 + (long)(n0 + r) * HID + k8 * 8);
    int kc = k8 >> 2, L = ((k8 & 3) << 4) | r;
    *(bf16x8*)(dst + ((kc * 64 + L) << 3)) = v;
  }
}

// ---- per-wave GEMM: A from global (pre-offset), W from frag-ordered LDS ----
__device__ __forceinline__ floatx4 gpair(const unsigned short* __restrict__ a1,
                                         const unsigned short* __restrict__ a2,
                                         const unsigned short* sW, int khalf, int lane) {
  floatx4 acc = {0.f, 0.f, 0.f, 0.f};
  const unsigned short* w1 = sW + (((khalf * 16) * 64 + lane) << 3);
  const unsigned short* w2 = sW + (((32 + khalf * 16) * 64 + lane) << 3);
  #pragma unroll
  for (int j = 0; j < 16; ++j)
    acc = __builtin_amdgcn_mfma_f32_16x16x32_bf16(*(const bf16x8*)(a1 + j * 32),
                                                  *(const bf16x8*)(w1 + j * 512), acc, 0, 0, 0);
  #pragma unroll
  for (int j = 0; j < 16; ++j)
    acc = __builtin_amdgcn_mfma_f32_16x16x32_bf16(*(const bf16x8*)(a2 + j * 32),
                                                  *(const bf16x8*)(w2 + j * 512), acc, 0, 0, 0);
  return acc;
}
__device__ __forceinline__ floatx4 gsingle(const unsigned short* __restrict__ a,
                                           const unsigned short* sW, int khalf, int lane) {
  floatx4 acc = {0.f, 0.f, 0.f, 0.f};
  const unsigned short* w = sW + (((khalf * 16) * 64 + lane) << 3);
  #pragma unroll
  for (int j = 0; j < 16; ++j)
    acc = __builtin_amdgcn_mfma_f32_16x16x32_bf16(*(const bf16x8*)(a + j * 32),
                                                  *(const bf16x8*)(w + j * 512), acc, 0, 0, 0);
  return acc;
}

// Persistent GRU, 256 blocks x 256 threads, LDS-resident weights.
// P roles (blk>>6): 0=z0, 1=r0, 2=z1, 3=r1; 16 cols each ((blk&63)*16).
// Q roles: 0=g0, 1=g1, 2=Y (16 cols, (blk-128)*16), 3=idle.
__global__ void __launch_bounds__(256, 1) gru2(
    const void* __restrict__ x, const void* __restrict__ h0i,
    const void* __restrict__ Wxz, const void* __restrict__ Wxr, const void* __restrict__ Wxg,
    const void* __restrict__ Whz, const void* __restrict__ Whr, const void* __restrict__ Whg,
    const void* __restrict__ bhz, const void* __restrict__ bhr, const void* __restrict__ bhg,
    const void* __restrict__ WY, const void* __restrict__ bY,
    void* __restrict__ out, const int* __restrict__ flagp, int* __restrict__ barBase,
    const unsigned short* __restrict__ xb, const unsigned short* __restrict__ wcv,
    const unsigned short* __restrict__ wyc,
    float* __restrict__ h0f, float* __restrict__ h1f,
    float* __restrict__ z0f, float* __restrict__ z1f,
    unsigned short* __restrict__ h0b, unsigned short* __restrict__ h1b,
    unsigned short* __restrict__ rh0, unsigned short* __restrict__ rh1)
{
  extern __shared__ char smem[];
  unsigned short* sWP = (unsigned short*)smem;             // 65536 B
  unsigned short* sWQ = (unsigned short*)(smem + 65536);   // 65536 B
  floatx4* red = (floatx4*)(smem + 131072);                // 4096 B

  // counter regions, each 8 lines x 256 B
  int* barCnt   = barBase;            // init barrier
  int* xcdArr   = barBase + 512;      // per-XCD arrival
  int* gCnt     = barBase + 1024;     // global (8-way split)
  int* xcdGo    = barBase + 2048;     // per-XCD go flag
  int* xcdCount = barBase + 2560;     // per-XCD block census

  const int flag = *flagp;
  const int thr  = threadIdx.x;
  const int wave = thr >> 6;
  const int lane = thr & 63;
  const int l15  = lane & 15;
  const int kq   = (lane >> 4) * 8;
  const int blk  = blockIdx.x;
  const int role = blk >> 6;
  const int c0   = (blk & 63) * 16;
  const bool evn = (lane & 1) == 0;
  // HW_REG_XCC_ID = hwreg 20, size 4
  const int myxcd = __builtin_amdgcn_s_getreg(20 | (3 << 11)) & 7;

  const unsigned short* xP  = flag ? xb                : (const unsigned short*)x;
  const unsigned short* Wzp = flag ? wcv + 0L*2097152  : (const unsigned short*)Wxz;
  const unsigned short* Wrp = flag ? wcv + 1L*2097152  : (const unsigned short*)Wxr;
  const unsigned short* Wgp = flag ? wcv + 2L*2097152  : (const unsigned short*)Wxg;
  const unsigned short* Uzp = flag ? wcv + 3L*2097152  : (const unsigned short*)Whz;
  const unsigned short* Urp = flag ? wcv + 4L*2097152  : (const unsigned short*)Whr;
  const unsigned short* Ugp = flag ? wcv + 5L*2097152  : (const unsigned short*)Whg;
  const unsigned short* WYp = flag ? wyc               : (const unsigned short*)WY;

  // ---- XCD census + leader election (old==0) ----
  int lead = 0;
  if (thr == 0) {
    int old = __hip_atomic_fetch_add(xcdCount + myxcd * 64, 1,
                                     __ATOMIC_RELAXED, __HIP_MEMORY_SCOPE_AGENT);
    lead = (old == 0);
  }

  // ---- one-time weight staging into LDS (block-local) ----
  {
    long off = (role >> 1) ? (long)HH : 0;
    const unsigned short* s0 = ((role & 1) ? Wrp : Wzp) + off;
    const unsigned short* s1 = ((role & 1) ? Urp : Uzp) + off;
    stage2(sWP, s0, s1, c0, thr);
  }
  if (blk < 128)      stage2(sWQ, Wgp + (blk >= 64 ? (long)HH : 0),
                             Ugp + (blk >= 64 ? (long)HH : 0), c0, thr);
  else if (blk < 192) stage1(sWQ, WYp, (blk - 128) * 16, thr);

  // ---- init hidden state (h_{-1}) into both parity buffers ----
  {
    int gtid = blk * 256 + thr;          // 0..65535
    int layer = gtid >> 15, i = gtid & 32767;
    float v = ldflag(h0i, (long)layer * NB + i, flag);
    unsigned int b = f2bf(v);
    if (layer == 0) { GSTW(h0f + i, v); GSTH(h0b + i, b); GSTH(h0b + NB + i, b); }
    else            { GSTW(h1f + i, v); GSTH(h1b + i, b); GSTH(h1b + NB + i, b); }
  }
  asm volatile("s_waitcnt vmcnt(0)" ::: "memory");
  gbar(barCnt, NBLK, blk);               // init barrier (full fences, proven)

  int xcdTot = 0;
  if (thr == 0)
    xcdTot = __hip_atomic_load(xcdCount + myxcd * 64, __ATOMIC_RELAXED, __HIP_MEMORY_SCOPE_AGENT);
  int pidx = 0;

  for (int s = 0; s < SEQ + 2; ++s) {
    const int pPrev  = ((s + 1) & 1) * NB;  // parity slot of h_{s-1}
    const int pPrev2 = (s & 1) * NB;        // parity slot of h_{s-2}
    const int mt = wave & 1, khalf = wave >> 1;
    const int m = mt * 16 + l15;
    const int aoff = kq + khalf * 512;

    // ================= interval P =================
    {
      const int layer = role >> 1, zr = role & 1;
      const bool active = layer ? (s >= 1 && s <= SEQ) : (s < SEQ);
      if (active) {
        const unsigned short *a1, *a2;
        if (layer == 0) {
          a1 = xP + (long)m * (SEQ * HID) + (long)s * HID + aoff;
          a2 = h0b + pPrev + m * HID + aoff;
        } else {
          a1 = h0b + pPrev + m * HID + aoff;
          a2 = h1b + pPrev2 + m * HID + aoff;
        }
        floatx4 acc = gpair(a1, a2, sWP, khalf, lane);
        red[wave * 64 + lane] = acc;
        __syncthreads();
        if (wave < 2) {
          floatx4 ss = red[wave * 64 + lane] + red[(wave + 2) * 64 + lane];
          int n = c0 + l15;
          float bv = ldflag(zr ? bhr : bhz, (long)layer * HID + n, flag);
          if (!zr) {                       // z0 / z1 (f32, pair-swapped)
            float* zdst = layer ? z1f : z0f;
            #pragma unroll
            for (int r = 0; r < 4; ++r) {
              int row = wave * 16 + (lane >> 4) * 4 + r;
              float v = sigmoidf_(ss[r] + bv);
              float vp = __shfl_xor(v, 1);
              if (evn) aswapF2(zdst + row * HID + n, v, vp);
            }
          } else {                         // r0/r1 -> rh (bf16, pair-swapped)
            const float* hsrc = layer ? h1f : h0f;
            unsigned short* rdst = layer ? rh1 : rh0;
            #pragma unroll
            for (int r = 0; r < 4; ++r) {
              int row = wave * 16 + (lane >> 4) * 4 + r;
              int idx = row * HID + n;
              unsigned sv = f2bf(sigmoidf_(ss[r] + bv) * hsrc[idx]);
              unsigned pv = __shfl_xor((int)sv, 1);
              if (evn) aswapH2(rdst + idx, sv, pv);
            }
          }
        }
      }
    }
    ++pidx; gbar3(xcdArr, gCnt, xcdGo, myxcd, xcdTot, lead, pidx);

    // ================= interval Q =================
    if (role == 0) {            // g0 + h0 update (step s)
      if (s < SEQ) {
        const unsigned short* a1 = xP + (long)m * (SEQ * HID) + (long)s * HID + aoff;
        const unsigned short* a2 = rh0 + m * HID + aoff;
        floatx4 acc = gpair(a1, a2, sWQ, khalf, lane);
        red[wave * 64 + lane] = acc;
        __syncthreads();
        if (wave < 2) {
          floatx4 ss = red[wave * 64 + lane] + red[(wave + 2) * 64 + lane];
          int n = c0 + l15;
          float bv = ldflag(bhg, n, flag);
          #pragma unroll
          for (int r = 0; r < 4; ++r) {
            int row = wave * 16 + (lane >> 4) * 4 + r;
            int idx = row * HID + n;
            float g = tanhf(ss[r] + bv);
            float z = z0f[idx], hp = h0f[idx];
            float hn = z * hp + (1.f - z) * g;
            float hnp = __shfl_xor(hn, 1);
            unsigned hb = f2bf(hn);
            unsigned hbp = __shfl_xor((int)hb, 1);
            if (evn) {
              aswapF2(h0f + idx, hn, hnp);
              aswapH2(h0b + (s & 1) * NB + idx, hb, hbp);
              if (s == SEQ - 1) {
                long o = 16777216L + (long)row * 2048 + n;
                if (flag) aswapF2((float*)out + o, hn, hnp);
                else      aswapH2((unsigned short*)out + o, hb, hbp);
              }
            }
          }
        }
      }
    } else if (role == 1) {     // g1 + h1 update (step s-1)
      if (s >= 1 && s <= SEQ) {
        const unsigned short* a1 = h0b + pPrev + m * HID + aoff;
        const unsigned short* a2 = rh1 + m * HID + aoff;
        floatx4 acc = gpair(a1, a2, sWQ, khalf, lane);
        red[wave * 64 + lane] = acc;
        __syncthreads();
        if (wave < 2) {
          floatx4 ss = red[wave * 64 + lane] + red[(wave + 2) * 64 + lane];
          int n = c0 + l15;
          float bv = ldflag(bhg, (long)HID + n, flag);
          #pragma unroll
          for (int r = 0; r < 4; ++r) {
            int row = wave * 16 + (lane >> 4) * 4 + r;
            int idx = row * HID + n;
            float g = tanhf(ss[r] + bv);
            float z = z1f[idx], hp = h1f[idx];
            float hn = z * hp + (1.f - z) * g;
            float hnp = __shfl_xor(hn, 1);
            unsigned hb = f2bf(hn);
            unsigned hbp = __shfl_xor((int)hb, 1);
            if (evn) {
              aswapF2(h1f + idx, hn, hnp);
              aswapH2(h1b + ((s + 1) & 1) * NB + idx, hb, hbp);
              if (s == SEQ) {
                long o = 16777216L + (long)row * 2048 + 1024 + n;
                if (flag) aswapF2((float*)out + o, hn, hnp);
                else      aswapH2((unsigned short*)out + o, hb, hbp);
              }
            }
          }
        }
      }
    } else if (role == 2) {     // Y_{s-2}
      if (s >= 2) {
        const int cy = (blk - 128) * 16;
        const unsigned short* a = h1b + pPrev2 + m * HID + aoff;
        floatx4 acc = gsingle(a, sWQ, khalf, lane);
        red[wave * 64 + lane] = acc;
        __syncthreads();
        if (wave < 2) {
          floatx4 ss = red[wave * 64 + lane] + red[(wave + 2) * 64 + lane];
          int n = cy + l15;
          float bv = ldflag(bY, n, flag);
          const int tY = s - 2;
          #pragma unroll
          for (int r = 0; r < 4; ++r) {
            int brow = wave * 16 + (lane >> 4) * 4 + r;
            long oidx = ((long)brow * SEQ + tY) * HID + n;
            float yv = ss[r] + bv;
            float yp = __shfl_xor(yv, 1);
            unsigned yb = f2bf(yv);
            unsigned ybp = __shfl_xor((int)yb, 1);
            if (evn) {
              if (flag) aswapF2((float*)out + oidx, yv, yp);
              else      aswapH2((unsigned short*)out + oidx, yb, ybp);
            }
          }
        }
      }
    }
    ++pidx; gbar3(xcdArr, gCnt, xcdGo, myxcd, xcdTot, lead, pidx);
  }
}

extern "C" void kernel_launch(void* const* d_in, const int* in_sizes, int n_in,
                              void* d_out, int out_size, void* d_ws, size_t ws_size,
                              hipStream_t stream) {
  const void* x   = d_in[0];
  const void* h0i = d_in[1];
  const void* Wxz = d_in[2];
  const void* Wxr = d_in[3];
  const void* Wxg = d_in[4];
  const void* Whz = d_in[5];
  const void* Whr = d_in[6];
  const void* Whg = d_in[7];
  const void* bhz = d_in[8];
  const void* bhr = d_in[9];
  const void* bhg = d_in[10];
  const void* WY  = d_in[11];
  const void* bY  = d_in[12];

  char* ws = (char*)d_ws;
  int* flag    = (int*)ws;
  int* barBase = (int*)(ws + 1024);   // regions x 8 lines x 256 B
  float* h0f = (float*)(ws + 16384);
  float* h1f = h0f + NB;
  float* z0f = h1f + NB;
  float* z1f = z0f + NB;
  unsigned short* h0b = (unsigned short*)(z1f + NB);  // 2*NB
  unsigned short* h1b = h0b + 2 * NB;                 // 2*NB
  unsigned short* rh0 = h1b + 2 * NB;
  unsigned short* rh1 = rh0 + NB;
  unsigned short* xb  = (unsigned short*)(ws + (1 << 20));
  unsigned short* wcv = xb + 16777216L;
  unsigned short* wyc = wcv + 12582912L;

  hipMemsetAsync(barBase, 0, 12288, stream);
  detect_k<<<1, 64, 0, stream>>>((const unsigned int*)x, flag);
  convert_k<<<2048, 256, 0, stream>>>((const float*)x,
      (const float*)Wxz, (const float*)Wxr, (const float*)Wxg,
      (const float*)Whz, (const float*)Whr, (const float*)Whg,
      (const float*)WY, xb, wcv, wyc, flag);

  static int attr_set = 0;
  if (!attr_set) {
    hipFuncSetAttribute((const void*)gru2, hipFuncAttributeMaxDynamicSharedMemorySize, 135168);
    attr_set = 1;
  }

  void* out = d_out;
  const int* flagc = flag;
  int* barc = barBase;
  void* args[] = { (void*)&x, (void*)&h0i, (void*)&Wxz, (void*)&Wxr, (void*)&Wxg,
                   (void*)&Whz, (void*)&Whr, (void*)&Whg, (void*)&bhz, (void*)&bhr,
                   (void*)&bhg, (void*)&WY, (void*)&bY, (void*)&out, (void*)&flagc,
                   (void*)&barc, (void*)&xb, (void*)&wcv, (void*)&wyc,
                   (void*)&h0f, (void*)&h1f, (void*)&z0f, (void*)&z1f,
                   (void*)&h0b, (void*)&h1b, (void*)&rh0, (void*)&rh1 };
  hipLaunchCooperativeKernel((const void*)gru2, dim3(NBLK), dim3(256), args, 135168, stream);
}

// Round 7
// 8649.347 us; speedup vs baseline: 1.2388x; 1.2388x over previous
//
#include <hip/hip_runtime.h>
#include <hip/hip_bf16.h>

typedef __bf16 bf16x8 __attribute__((ext_vector_type(8)));
typedef float floatx4 __attribute__((ext_vector_type(4)));

#define HID 1024
#define HH (1024*1024)
#define SEQ 512
#define NB 32768  /* 32*1024 state elements */
#define NBLK 256

__device__ __forceinline__ float bf2f(unsigned short u) {
  union { unsigned int i; float f; } v; v.i = ((unsigned int)u) << 16; return v.f;
}
__device__ __forceinline__ unsigned short f2bf(float f) {
  union { float f; unsigned int i; } v; v.f = f;
  unsigned int i = v.i;
  return (unsigned short)((i + 0x7fffu + ((i >> 16) & 1u)) >> 16);
}
__device__ __forceinline__ float ldflag(const void* p, long i, int flag) {
  return flag ? ((const float*)p)[i] : bf2f(((const unsigned short*)p)[i]);
}
__device__ __forceinline__ float sigmoidf_(float x) { return 1.0f / (1.0f + __expf(-x)); }

// plain stores (r3/r5 proven path; release wbl2 at the barrier flushes them)
#define GSTH(p_, v_)   asm volatile("global_store_short %0, %1, off sc0 sc1" :: "v"(p_), "v"(v_) : "memory")
#define GSTW(p_, v_)   asm volatile("global_store_dword %0, %1, off sc0 sc1" :: "v"(p_), "v"(v_) : "memory")

__device__ __forceinline__ void outw_wt(void* out, int flag, long idx, float v) {
  if (flag) { GSTW((float*)out + idx, v); }
  else      { GSTH((unsigned short*)out + idx, (unsigned int)f2bf(v)); }
}

// ---- dtype detection: bf16 (flag=0) vs fp32 (flag=1) ----
__global__ void detect_k(const unsigned int* __restrict__ xw, int* __restrict__ flag) {
  unsigned int w = xw[threadIdx.x];
  int e = (w >> 7) & 0xFF;
  int ok = (e >= 100 && e <= 141) ? 1 : 0;
  unsigned long long m = __ballot(ok);
  if (threadIdx.x == 0) *flag = (__popcll(m) >= 36) ? 0 : 1;
}

// ---- fp32 -> bf16 conversion of x, 6 weight tensors, WY (no-op when flag=0) ----
__global__ void convert_k(const float* __restrict__ x,
                          const float* __restrict__ w0, const float* __restrict__ w1,
                          const float* __restrict__ w2, const float* __restrict__ w3,
                          const float* __restrict__ w4, const float* __restrict__ w5,
                          const float* __restrict__ wy,
                          unsigned short* __restrict__ xb, unsigned short* __restrict__ wc,
                          unsigned short* __restrict__ wyc, const int* __restrict__ flag) {
  if (*flag == 0) return;
  const float* Ws[6] = { w0, w1, w2, w3, w4, w5 };
  const long total = 3801088;
  for (long c = (long)blockIdx.x * 256 + threadIdx.x; c < total; c += (long)gridDim.x * 256) {
    long e = c * 8;
    const float* src; unsigned short* dst; long off;
    if (e < 16777216)      { src = x;  dst = xb;  off = e; }
    else if (e < 29360128) { long r = e - 16777216; int wi = (int)(r >> 21);
                             src = Ws[wi]; dst = wc + (long)wi * 2097152; off = r & 2097151; }
    else                   { src = wy; dst = wyc; off = e - 29360128; }
    float4 a = *(const float4*)(src + off);
    float4 b = *(const float4*)(src + off + 4);
    uint4 o;
    o.x = (unsigned)f2bf(a.x) | ((unsigned)f2bf(a.y) << 16);
    o.y = (unsigned)f2bf(a.z) | ((unsigned)f2bf(a.w) << 16);
    o.z = (unsigned)f2bf(b.x) | ((unsigned)f2bf(b.y) << 16);
    o.w = (unsigned)f2bf(b.z) | ((unsigned)f2bf(b.w) << 16);
    *(uint4*)(dst + off) = o;
  }
}

// ---- init-time grid barrier: round-3 proven (full fences per block) ----
__device__ __forceinline__ void gbar(int* cnt, int target, int blk) {
  __syncthreads();
  if (threadIdx.x == 0) {
    __builtin_amdgcn_fence(__ATOMIC_RELEASE, "agent");
    __hip_atomic_fetch_add(cnt + (blk & 7) * 64, 1, __ATOMIC_RELAXED, __HIP_MEMORY_SCOPE_AGENT);
    int ssum;
    do {
      ssum = 0;
      #pragma unroll
      for (int i = 0; i < 8; ++i)
        ssum += __hip_atomic_load(cnt + i * 64, __ATOMIC_RELAXED, __HIP_MEMORY_SCOPE_AGENT);
      if (ssum < target) __builtin_amdgcn_s_sleep(1);
    } while (ssum < target);
    __builtin_amdgcn_fence(__ATOMIC_ACQUIRE, "agent");
  }
  __syncthreads();
}

// ---- per-phase hierarchical barrier, NO ticket round (r7).
// release: LAST ARRIVER per XCD (knows from its fetch_add return - no extra
// hop) runs the release fence (wbl2: flush this XCD's dirty state to the IF)
// and posts the XCD's count to ONE global line (8 posters total).
// acquire: fixed per-XCD LEADER polls the global line, runs the acquire fence
// (L2+L1 inv), posts go. MEMBERS: own-CU L1 buffer_inv issued EARLY (off the
// critical path), then poll go only. The r5 per-member ticket RMW round
// (32 serialized same-line RMWs/XCD on every member's critical path) is gone.
__device__ __forceinline__ void gbar7(int* xcdArr, int* gTot, int* xcdGo,
                                      int myxcd, int xcdTot, int lead, int pidx) {
  asm volatile("s_waitcnt vmcnt(0)" ::: "memory");  // this wave's stores -> L2
  __syncthreads();                                  // all waves drained
  if (threadIdx.x == 0) {
    int old = __hip_atomic_fetch_add(xcdArr + myxcd * 64, 1,
                                     __ATOMIC_RELAXED, __HIP_MEMORY_SCOPE_AGENT);
    if (old == pidx * xcdTot - 1) {                 // last arriver on this XCD
      __builtin_amdgcn_fence(__ATOMIC_RELEASE, "agent");    // wbl2 + wait
      __hip_atomic_fetch_add(gTot, xcdTot, __ATOMIC_RELAXED, __HIP_MEMORY_SCOPE_AGENT);
    }
    if (lead) {
      while (__hip_atomic_load(gTot, __ATOMIC_RELAXED, __HIP_MEMORY_SCOPE_AGENT)
             < NBLK * pidx)
        __builtin_amdgcn_s_sleep(1);
      __builtin_amdgcn_fence(__ATOMIC_ACQUIRE, "agent");    // L2+L1 inv
      __hip_atomic_store(xcdGo + myxcd * 64, pidx,
                         __ATOMIC_RELAXED, __HIP_MEMORY_SCOPE_AGENT);
    } else {
      asm volatile("buffer_inv" ::: "memory");      // own-CU L1 inv, early
      while (__hip_atomic_load(xcdGo + myxcd * 64, __ATOMIC_RELAXED,
                               __HIP_MEMORY_SCOPE_AGENT) < pidx)
        __builtin_amdgcn_s_sleep(1);
    }
  }
  __syncthreads();
}

// ---- stage a (W,U) pair of 16 rows x K=1024 each into MFMA-frag-ordered LDS ----
// frag layout (ushort idx): ((m*32 + kc)*64 + L)*8, kc=k>>5, L=((k>>3)&3)*16 | row
__device__ __forceinline__ void stage2(unsigned short* dst,
                                       const unsigned short* __restrict__ s0,
                                       const unsigned short* __restrict__ s1,
                                       int n0, int tid) {
  const unsigned short* srcs[2] = { s0, s1 };
  #pragma unroll
  for (int i = 0; i < 16; ++i) {
    int idx = i * 256 + tid;          // 0..4095: 2 matrices x 16 rows x 128 k8
    int m = idx >> 11;
    int rem = idx & 2047;
    int r = rem >> 7, k8 = rem & 127;
    bf16x8 v = *(const bf16x8*)(srcs[m] + (long)(n0 + r) * HID + k8 * 8);
    int kc = k8 >> 2, L = ((k8 & 3) << 4) | r;
    *(bf16x8*)(dst + (((m * 32 + kc) * 64 + L) << 3)) = v;
  }
}
__device__ __forceinline__ void stage1(unsigned short* dst,
                                       const unsigned short* __restrict__ s0,
                                       int n0, int tid) {
  #pragma unroll
  for (int i = 0; i < 8; ++i) {
    int idx = i * 256 + tid;          // 0..2047
    int r = idx >> 7, k8 = idx & 127;
    bf16x8 v = *(const bf16x8*)(s0 + (long)(n0 + r) * HID + k8 * 8);
    int kc = k8 >> 2, L = ((k8 & 3) << 4) | r;
    *(bf16x8*)(dst + ((kc * 64 + L) << 3)) = v;
  }
}

// ---- per-wave GEMM: A from global (pre-offset), W from frag-ordered LDS ----
__device__ __forceinline__ floatx4 gpair(const unsigned short* __restrict__ a1,
                                         const unsigned short* __restrict__ a2,
                                         const unsigned short* sW, int khalf, int lane) {
  floatx4 acc = {0.f, 0.f, 0.f, 0.f};
  const unsigned short* w1 = sW + (((khalf * 16) * 64 + lane) << 3);
  const unsigned short* w2 = sW + (((32 + khalf * 16) * 64 + lane) << 3);
  #pragma unroll
  for (int j = 0; j < 16; ++j)
    acc = __builtin_amdgcn_mfma_f32_16x16x32_bf16(*(const bf16x8*)(a1 + j * 32),
                                                  *(const bf16x8*)(w1 + j * 512), acc, 0, 0, 0);
  #pragma unroll
  for (int j = 0; j < 16; ++j)
    acc = __builtin_amdgcn_mfma_f32_16x16x32_bf16(*(const bf16x8*)(a2 + j * 32),
                                                  *(const bf16x8*)(w2 + j * 512), acc, 0, 0, 0);
  return acc;
}
__device__ __forceinline__ floatx4 gsingle(const unsigned short* __restrict__ a,
                                           const unsigned short* sW, int khalf, int lane) {
  floatx4 acc = {0.f, 0.f, 0.f, 0.f};
  const unsigned short* w = sW + (((khalf * 16) * 64 + lane) << 3);
  #pragma unroll
  for (int j = 0; j < 16; ++j)
    acc = __builtin_amdgcn_mfma_f32_16x16x32_bf16(*(const bf16x8*)(a + j * 32),
                                                  *(const bf16x8*)(w + j * 512), acc, 0, 0, 0);
  return acc;
}

// Persistent GRU, 256 blocks x 256 threads, LDS-resident weights.
// P roles (blk>>6): 0=z0, 1=r0, 2=z1, 3=r1; 16 cols each ((blk&63)*16).
// Q roles: 0=g0, 1=g1, 2=Y (16 cols, (blk-128)*16), 3=idle.
__global__ void __launch_bounds__(256, 1) gru2(
    const void* __restrict__ x, const void* __restrict__ h0i,
    const void* __restrict__ Wxz, const void* __restrict__ Wxr, const void* __restrict__ Wxg,
    const void* __restrict__ Whz, const void* __restrict__ Whr, const void* __restrict__ Whg,
    const void* __restrict__ bhz, const void* __restrict__ bhr, const void* __restrict__ bhg,
    const void* __restrict__ WY, const void* __restrict__ bY,
    void* __restrict__ out, const int* __restrict__ flagp, int* __restrict__ barBase,
    const unsigned short* __restrict__ xb, const unsigned short* __restrict__ wcv,
    const unsigned short* __restrict__ wyc,
    float* __restrict__ h0f, float* __restrict__ h1f,
    float* __restrict__ z0f, float* __restrict__ z1f,
    unsigned short* __restrict__ h0b, unsigned short* __restrict__ h1b,
    unsigned short* __restrict__ rh0, unsigned short* __restrict__ rh1)
{
  extern __shared__ char smem[];
  unsigned short* sWP = (unsigned short*)smem;             // 65536 B
  unsigned short* sWQ = (unsigned short*)(smem + 65536);   // 65536 B
  floatx4* red = (floatx4*)(smem + 131072);                // 4096 B

  // counter regions (256 B lines)
  int* barCnt   = barBase;            // init barrier (8 lines)
  int* xcdArr   = barBase + 512;      // per-XCD arrival (8 lines)
  int* gTot     = barBase + 1024;     // single global line (8 posters only)
  int* xcdGo    = barBase + 2048;     // per-XCD go flag (8 lines)
  int* xcdCount = barBase + 2560;     // per-XCD block census (8 lines)

  const int flag = *flagp;
  const int thr  = threadIdx.x;
  const int wave = thr >> 6;
  const int lane = thr & 63;
  const int l15  = lane & 15;
  const int kq   = (lane >> 4) * 8;
  const int blk  = blockIdx.x;
  const int role = blk >> 6;
  const int c0   = (blk & 63) * 16;
  // HW_REG_XCC_ID = hwreg 20, size 4
  const int myxcd = __builtin_amdgcn_s_getreg(20 | (3 << 11)) & 7;

  const unsigned short* xP  = flag ? xb                : (const unsigned short*)x;
  const unsigned short* Wzp = flag ? wcv + 0L*2097152  : (const unsigned short*)Wxz;
  const unsigned short* Wrp = flag ? wcv + 1L*2097152  : (const unsigned short*)Wxr;
  const unsigned short* Wgp = flag ? wcv + 2L*2097152  : (const unsigned short*)Wxg;
  const unsigned short* Uzp = flag ? wcv + 3L*2097152  : (const unsigned short*)Whz;
  const unsigned short* Urp = flag ? wcv + 4L*2097152  : (const unsigned short*)Whr;
  const unsigned short* Ugp = flag ? wcv + 5L*2097152  : (const unsigned short*)Whg;
  const unsigned short* WYp = flag ? wyc               : (const unsigned short*)WY;

  // ---- XCD census + leader election (old==0) ----
  int lead = 0;
  if (thr == 0) {
    int old = __hip_atomic_fetch_add(xcdCount + myxcd * 64, 1,
                                     __ATOMIC_RELAXED, __HIP_MEMORY_SCOPE_AGENT);
    lead = (old == 0);
  }

  // ---- one-time weight staging into LDS (block-local) ----
  {
    long off = (role >> 1) ? (long)HH : 0;
    const unsigned short* s0 = ((role & 1) ? Wrp : Wzp) + off;
    const unsigned short* s1 = ((role & 1) ? Urp : Uzp) + off;
    stage2(sWP, s0, s1, c0, thr);
  }
  if (blk < 128)      stage2(sWQ, Wgp + (blk >= 64 ? (long)HH : 0),
                             Ugp + (blk >= 64 ? (long)HH : 0), c0, thr);
  else if (blk < 192) stage1(sWQ, WYp, (blk - 128) * 16, thr);

  // ---- init hidden state (h_{-1}) into both parity buffers ----
  {
    int gtid = blk * 256 + thr;          // 0..65535
    int layer = gtid >> 15, i = gtid & 32767;
    float v = ldflag(h0i, (long)layer * NB + i, flag);
    unsigned int b = f2bf(v);
    if (layer == 0) { GSTW(h0f + i, v); GSTH(h0b + i, b); GSTH(h0b + NB + i, b); }
    else            { GSTW(h1f + i, v); GSTH(h1b + i, b); GSTH(h1b + NB + i, b); }
  }
  asm volatile("s_waitcnt vmcnt(0)" ::: "memory");
  gbar(barCnt, NBLK, blk);               // init barrier (full fences, proven)

  int xcdTot = 0;
  if (thr == 0)
    xcdTot = __hip_atomic_load(xcdCount + myxcd * 64, __ATOMIC_RELAXED, __HIP_MEMORY_SCOPE_AGENT);
  int pidx = 0;

  for (int s = 0; s < SEQ + 2; ++s) {
    const int pPrev  = ((s + 1) & 1) * NB;  // parity slot of h_{s-1}
    const int pPrev2 = (s & 1) * NB;        // parity slot of h_{s-2}
    const int mt = wave & 1, khalf = wave >> 1;
    const int m = mt * 16 + l15;
    const int aoff = kq + khalf * 512;

    // ================= interval P =================
    {
      const int layer = role >> 1, zr = role & 1;
      const bool active = layer ? (s >= 1 && s <= SEQ) : (s < SEQ);
      if (active) {
        const unsigned short *a1, *a2;
        if (layer == 0) {
          a1 = xP + (long)m * (SEQ * HID) + (long)s * HID + aoff;
          a2 = h0b + pPrev + m * HID + aoff;
        } else {
          a1 = h0b + pPrev + m * HID + aoff;
          a2 = h1b + pPrev2 + m * HID + aoff;
        }
        floatx4 acc = gpair(a1, a2, sWP, khalf, lane);
        red[wave * 64 + lane] = acc;
        __syncthreads();
        if (wave < 2) {
          floatx4 ss = red[wave * 64 + lane] + red[(wave + 2) * 64 + lane];
          int n = c0 + l15;
          float bv = ldflag(zr ? bhr : bhz, (long)layer * HID + n, flag);
          #pragma unroll
          for (int r = 0; r < 4; ++r) {
            int row = wave * 16 + (lane >> 4) * 4 + r;
            int idx = row * HID + n;
            float v = sigmoidf_(ss[r] + bv);
            if (role == 0)      GSTW(z0f + idx, v);
            else if (role == 1) GSTH(rh0 + idx, (unsigned int)f2bf(v * h0f[idx]));
            else if (role == 2) GSTW(z1f + idx, v);
            else                GSTH(rh1 + idx, (unsigned int)f2bf(v * h1f[idx]));
          }
        }
      }
    }
    ++pidx; gbar7(xcdArr, gTot, xcdGo, myxcd, xcdTot, lead, pidx);

    // ================= interval Q =================
    if (role == 0) {            // g0 + h0 update (step s)
      if (s < SEQ) {
        const unsigned short* a1 = xP + (long)m * (SEQ * HID) + (long)s * HID + aoff;
        const unsigned short* a2 = rh0 + m * HID + aoff;
        floatx4 acc = gpair(a1, a2, sWQ, khalf, lane);
        red[wave * 64 + lane] = acc;
        __syncthreads();
        if (wave < 2) {
          floatx4 ss = red[wave * 64 + lane] + red[(wave + 2) * 64 + lane];
          int n = c0 + l15;
          float bv = ldflag(bhg, n, flag);
          #pragma unroll
          for (int r = 0; r < 4; ++r) {
            int row = wave * 16 + (lane >> 4) * 4 + r;
            int idx = row * HID + n;
            float g = tanhf(ss[r] + bv);
            float z = z0f[idx], hp = h0f[idx];
            float hn = z * hp + (1.f - z) * g;
            GSTW(h0f + idx, hn);
            GSTH(h0b + (s & 1) * NB + idx, (unsigned int)f2bf(hn));
            if (s == SEQ - 1) outw_wt(out, flag, 16777216L + (long)row * 2048 + n, hn);
          }
        }
      }
    } else if (role == 1) {     // g1 + h1 update (step s-1)
      if (s >= 1 && s <= SEQ) {
        const unsigned short* a1 = h0b + pPrev + m * HID + aoff;
        const unsigned short* a2 = rh1 + m * HID + aoff;
        floatx4 acc = gpair(a1, a2, sWQ, khalf, lane);
        red[wave * 64 + lane] = acc;
        __syncthreads();
        if (wave < 2) {
          floatx4 ss = red[wave * 64 + lane] + red[(wave + 2) * 64 + lane];
          int n = c0 + l15;
          float bv = ldflag(bhg, (long)HID + n, flag);
          #pragma unroll
          for (int r = 0; r < 4; ++r) {
            int row = wave * 16 + (lane >> 4) * 4 + r;
            int idx = row * HID + n;
            float g = tanhf(ss[r] + bv);
            float z = z1f[idx], hp = h1f[idx];
            float hn = z * hp + (1.f - z) * g;
            GSTW(h1f + idx, hn);
            GSTH(h1b + ((s + 1) & 1) * NB + idx, (unsigned int)f2bf(hn));
            if (s == SEQ) outw_wt(out, flag, 16777216L + (long)row * 2048 + 1024 + n, hn);
          }
        }
      }
    } else if (role == 2) {     // Y_{s-2}
      if (s >= 2) {
        const int cy = (blk - 128) * 16;
        const unsigned short* a = h1b + pPrev2 + m * HID + aoff;
        floatx4 acc = gsingle(a, sWQ, khalf, lane);
        red[wave * 64 + lane] = acc;
        __syncthreads();
        if (wave < 2) {
          floatx4 ss = red[wave * 64 + lane] + red[(wave + 2) * 64 + lane];
          int n = cy + l15;
          float bv = ldflag(bY, n, flag);
          const int tY = s - 2;
          #pragma unroll
          for (int r = 0; r < 4; ++r) {
            int brow = wave * 16 + (lane >> 4) * 4 + r;
            long oidx = ((long)brow * SEQ + tY) * HID + n;
            outw_wt(out, flag, oidx, ss[r] + bv);
          }
        }
      }
    }
    ++pidx; gbar7(xcdArr, gTot, xcdGo, myxcd, xcdTot, lead, pidx);
  }
}

extern "C" void kernel_launch(void* const* d_in, const int* in_sizes, int n_in,
                              void* d_out, int out_size, void* d_ws, size_t ws_size,
                              hipStream_t stream) {
  const void* x   = d_in[0];
  const void* h0i = d_in[1];
  const void* Wxz = d_in[2];
  const void* Wxr = d_in[3];
  const void* Wxg = d_in[4];
  const void* Whz = d_in[5];
  const void* Whr = d_in[6];
  const void* Whg = d_in[7];
  const void* bhz = d_in[8];
  const void* bhr = d_in[9];
  const void* bhg = d_in[10];
  const void* WY  = d_in[11];
  const void* bY  = d_in[12];

  char* ws = (char*)d_ws;
  int* flag    = (int*)ws;
  int* barBase = (int*)(ws + 1024);   // counter regions, 256 B lines
  float* h0f = (float*)(ws + 16384);
  float* h1f = h0f + NB;
  float* z0f = h1f + NB;
  float* z1f = z0f + NB;
  unsigned short* h0b = (unsigned short*)(z1f + NB);  // 2*NB
  unsigned short* h1b = h0b + 2 * NB;                 // 2*NB
  unsigned short* rh0 = h1b + 2 * NB;
  unsigned short* rh1 = rh0 + NB;
  unsigned short* xb  = (unsigned short*)(ws + (1 << 20));
  unsigned short* wcv = xb + 16777216L;
  unsigned short* wyc = wcv + 12582912L;

  hipMemsetAsync(barBase, 0, 12288, stream);
  detect_k<<<1, 64, 0, stream>>>((const unsigned int*)x, flag);
  convert_k<<<2048, 256, 0, stream>>>((const float*)x,
      (const float*)Wxz, (const float*)Wxr, (const float*)Wxg,
      (const float*)Whz, (const float*)Whr, (const float*)Whg,
      (const float*)WY, xb, wcv, wyc, flag);

  static int attr_set = 0;
  if (!attr_set) {
    hipFuncSetAttribute((const void*)gru2, hipFuncAttributeMaxDynamicSharedMemorySize, 135168);
    attr_set = 1;
  }

  void* out = d_out;
  const int* flagc = flag;
  int* barc = barBase;
  void* args[] = { (void*)&x, (void*)&h0i, (void*)&Wxz, (void*)&Wxr, (void*)&Wxg,
                   (void*)&Whz, (void*)&Whr, (void*)&Whg, (void*)&bhz, (void*)&bhr,
                   (void*)&bhg, (void*)&WY, (void*)&bY, (void*)&out, (void*)&flagc,
                   (void*)&barc, (void*)&xb, (void*)&wcv, (void*)&wyc,
                   (void*)&h0f, (void*)&h1f, (void*)&z0f, (void*)&z1f,
                   (void*)&h0b, (void*)&h1b, (void*)&rh0, (void*)&rh1 };
  hipLaunchCooperativeKernel((const void*)gru2, dim3(NBLK), dim3(256), args, 135168, stream);
}

// Round 8
// 8615.194 us; speedup vs baseline: 1.2437x; 1.0040x over previous
//
#include <hip/hip_runtime.h>
#include <hip/hip_bf16.h>

typedef __bf16 bf16x8 __attribute__((ext_vector_type(8)));
typedef float floatx4 __attribute__((ext_vector_type(4)));

#define HID 1024
#define HH (1024*1024)
#define SEQ 512
#define NB 32768  /* 32*1024 state elements */
#define NBLK 256
#define SL(k) ((((k) & 3)) * NB)   /* generation slot (element offset) */

__device__ __forceinline__ float bf2f(unsigned short u) {
  union { unsigned int i; float f; } v; v.i = ((unsigned int)u) << 16; return v.f;
}
__device__ __forceinline__ unsigned short f2bf(float f) {
  union { float f; unsigned int i; } v; v.f = f;
  unsigned int i = v.i;
  return (unsigned short)((i + 0x7fffu + ((i >> 16) & 1u)) >> 16);
}
__device__ __forceinline__ float ldflag(const void* p, long i, int flag) {
  return flag ? ((const float*)p)[i] : bf2f(((const unsigned short*)p)[i]);
}
__device__ __forceinline__ float sigmoidf_(float x) { return 1.0f / (1.0f + __expf(-x)); }

// plain stores (r3/r5/r7 proven path; release wbl2 at the barrier flushes them)
#define GSTH(p_, v_)   asm volatile("global_store_short %0, %1, off sc0 sc1" :: "v"(p_), "v"(v_) : "memory")
#define GSTW(p_, v_)   asm volatile("global_store_dword %0, %1, off sc0 sc1" :: "v"(p_), "v"(v_) : "memory")

__device__ __forceinline__ void outw_wt(void* out, int flag, long idx, float v) {
  if (flag) { GSTW((float*)out + idx, v); }
  else      { GSTH((unsigned short*)out + idx, (unsigned int)f2bf(v)); }
}

// ---- dtype detection: bf16 (flag=0) vs fp32 (flag=1) ----
__global__ void detect_k(const unsigned int* __restrict__ xw, int* __restrict__ flag) {
  unsigned int w = xw[threadIdx.x];
  int e = (w >> 7) & 0xFF;
  int ok = (e >= 100 && e <= 141) ? 1 : 0;
  unsigned long long m = __ballot(ok);
  if (threadIdx.x == 0) *flag = (__popcll(m) >= 36) ? 0 : 1;
}

// ---- fp32 -> bf16 conversion of x, 6 weight tensors, WY (no-op when flag=0) ----
__global__ void convert_k(const float* __restrict__ x,
                          const float* __restrict__ w0, const float* __restrict__ w1,
                          const float* __restrict__ w2, const float* __restrict__ w3,
                          const float* __restrict__ w4, const float* __restrict__ w5,
                          const float* __restrict__ wy,
                          unsigned short* __restrict__ xb, unsigned short* __restrict__ wc,
                          unsigned short* __restrict__ wyc, const int* __restrict__ flag) {
  if (*flag == 0) return;
  const float* Ws[6] = { w0, w1, w2, w3, w4, w5 };
  const long total = 3801088;
  for (long c = (long)blockIdx.x * 256 + threadIdx.x; c < total; c += (long)gridDim.x * 256) {
    long e = c * 8;
    const float* src; unsigned short* dst; long off;
    if (e < 16777216)      { src = x;  dst = xb;  off = e; }
    else if (e < 29360128) { long r = e - 16777216; int wi = (int)(r >> 21);
                             src = Ws[wi]; dst = wc + (long)wi * 2097152; off = r & 2097151; }
    else                   { src = wy; dst = wyc; off = e - 29360128; }
    float4 a = *(const float4*)(src + off);
    float4 b = *(const float4*)(src + off + 4);
    uint4 o;
    o.x = (unsigned)f2bf(a.x) | ((unsigned)f2bf(a.y) << 16);
    o.y = (unsigned)f2bf(a.z) | ((unsigned)f2bf(a.w) << 16);
    o.z = (unsigned)f2bf(b.x) | ((unsigned)f2bf(b.y) << 16);
    o.w = (unsigned)f2bf(b.z) | ((unsigned)f2bf(b.w) << 16);
    *(uint4*)(dst + off) = o;
  }
}

// ---- init-time grid barrier: round-3 proven (full fences per block) ----
__device__ __forceinline__ void gbar(int* cnt, int target, int blk) {
  __syncthreads();
  if (threadIdx.x == 0) {
    __builtin_amdgcn_fence(__ATOMIC_RELEASE, "agent");
    __hip_atomic_fetch_add(cnt + (blk & 7) * 64, 1, __ATOMIC_RELAXED, __HIP_MEMORY_SCOPE_AGENT);
    int ssum;
    do {
      ssum = 0;
      #pragma unroll
      for (int i = 0; i < 8; ++i)
        ssum += __hip_atomic_load(cnt + i * 64, __ATOMIC_RELAXED, __HIP_MEMORY_SCOPE_AGENT);
      if (ssum < target) __builtin_amdgcn_s_sleep(1);
    } while (ssum < target);
    __builtin_amdgcn_fence(__ATOMIC_ACQUIRE, "agent");
  }
  __syncthreads();
}

// ---- per-phase barrier (r8): release wbl2 every phase (last-arriver/XCD),
// acquire L2-inv only every 4th phase. Address rotation (R=4 step slots on
// all cross-block state) guarantees any cached line is invalidated (gap <= 4
// phases) long before its slot is rewritten (8 phases). On non-inv phases
// everyone does only a cheap own-CU L1 buffer_inv. Ordering is unchanged from
// r7: the inv can only run after all 8 XCDs' wbl2 posted -> nothing dirty is
// ever discarded.
__device__ __forceinline__ void gbar8(int* xcdArr, int* gTot, int* xcdGo,
                                      int myxcd, int xcdTot, int lead, int pidx) {
  asm volatile("s_waitcnt vmcnt(0)" ::: "memory");  // this wave's stores -> L2
  __syncthreads();                                  // all waves drained
  if (threadIdx.x == 0) {
    int old = __hip_atomic_fetch_add(xcdArr + myxcd * 64, 1,
                                     __ATOMIC_RELAXED, __HIP_MEMORY_SCOPE_AGENT);
    if (old == pidx * xcdTot - 1) {                 // last arriver on this XCD
      __builtin_amdgcn_fence(__ATOMIC_RELEASE, "agent");    // wbl2 + wait
      __hip_atomic_fetch_add(gTot, xcdTot, __ATOMIC_RELAXED, __HIP_MEMORY_SCOPE_AGENT);
    }
    if (lead) {
      while (__hip_atomic_load(gTot, __ATOMIC_RELAXED, __HIP_MEMORY_SCOPE_AGENT)
             < NBLK * pidx)
        __builtin_amdgcn_s_sleep(1);
      if ((pidx & 3) == 0)
        __builtin_amdgcn_fence(__ATOMIC_ACQUIRE, "agent");  // L2+L1 inv, 1-in-4
      else
        asm volatile("buffer_inv" ::: "memory");            // L1 only
      __hip_atomic_store(xcdGo + myxcd * 64, pidx,
                         __ATOMIC_RELAXED, __HIP_MEMORY_SCOPE_AGENT);
    } else {
      asm volatile("buffer_inv" ::: "memory");      // own-CU L1 inv, early
      while (__hip_atomic_load(xcdGo + myxcd * 64, __ATOMIC_RELAXED,
                               __HIP_MEMORY_SCOPE_AGENT) < pidx)
        __builtin_amdgcn_s_sleep(1);
    }
  }
  __syncthreads();
}

// ---- stage a (W,U) pair of 16 rows x K=1024 each into MFMA-frag-ordered LDS ----
// frag layout (ushort idx): ((m*32 + kc)*64 + L)*8, kc=k>>5, L=((k>>3)&3)*16 | row
__device__ __forceinline__ void stage2(unsigned short* dst,
                                       const unsigned short* __restrict__ s0,
                                       const unsigned short* __restrict__ s1,
                                       int n0, int tid) {
  const unsigned short* srcs[2] = { s0, s1 };
  #pragma unroll
  for (int i = 0; i < 16; ++i) {
    int idx = i * 256 + tid;          // 0..4095: 2 matrices x 16 rows x 128 k8
    int m = idx >> 11;
    int rem = idx & 2047;
    int r = rem >> 7, k8 = rem & 127;
    bf16x8 v = *(const bf16x8*)(srcs[m] + (long)(n0 + r) * HID + k8 * 8);
    int kc = k8 >> 2, L = ((k8 & 3) << 4) | r;
    *(bf16x8*)(dst + (((m * 32 + kc) * 64 + L) << 3)) = v;
  }
}
__device__ __forceinline__ void stage1(unsigned short* dst,
                                       const unsigned short* __restrict__ s0,
                                       int n0, int tid) {
  #pragma unroll
  for (int i = 0; i < 8; ++i) {
    int idx = i * 256 + tid;          // 0..2047
    int r = idx >> 7, k8 = idx & 127;
    bf16x8 v = *(const bf16x8*)(s0 + (long)(n0 + r) * HID + k8 * 8);
    int kc = k8 >> 2, L = ((k8 & 3) << 4) | r;
    *(bf16x8*)(dst + ((kc * 64 + L) << 3)) = v;
  }
}

// ---- per-wave GEMM: A from global (pre-offset), W from frag-ordered LDS ----
__device__ __forceinline__ floatx4 gpair(const unsigned short* __restrict__ a1,
                                         const unsigned short* __restrict__ a2,
                                         const unsigned short* sW, int khalf, int lane) {
  floatx4 acc = {0.f, 0.f, 0.f, 0.f};
  const unsigned short* w1 = sW + (((khalf * 16) * 64 + lane) << 3);
  const unsigned short* w2 = sW + (((32 + khalf * 16) * 64 + lane) << 3);
  #pragma unroll
  for (int j = 0; j < 16; ++j)
    acc = __builtin_amdgcn_mfma_f32_16x16x32_bf16(*(const bf16x8*)(a1 + j * 32),
                                                  *(const bf16x8*)(w1 + j * 512), acc, 0, 0, 0);
  #pragma unroll
  for (int j = 0; j < 16; ++j)
    acc = __builtin_amdgcn_mfma_f32_16x16x32_bf16(*(const bf16x8*)(a2 + j * 32),
                                                  *(const bf16x8*)(w2 + j * 512), acc, 0, 0, 0);
  return acc;
}
__device__ __forceinline__ floatx4 gsingle(const unsigned short* __restrict__ a,
                                           const unsigned short* sW, int khalf, int lane) {
  floatx4 acc = {0.f, 0.f, 0.f, 0.f};
  const unsigned short* w = sW + (((khalf * 16) * 64 + lane) << 3);
  #pragma unroll
  for (int j = 0; j < 16; ++j)
    acc = __builtin_amdgcn_mfma_f32_16x16x32_bf16(*(const bf16x8*)(a + j * 32),
                                                  *(const bf16x8*)(w + j * 512), acc, 0, 0, 0);
  return acc;
}

// Persistent GRU, 256 blocks x 256 threads, LDS-resident weights.
// P roles (blk>>6): 0=z0, 1=r0, 2=z1, 3=r1; 16 cols each ((blk&63)*16).
// Q roles: 0=g0, 1=g1, 2=Y (16 cols, (blk-128)*16), 3=idle.
// State rotation (R=4 step slots): h0b,h1b,rh0,rh1,z1f,h0f,h1f. z0f single-slot
// (same-block producer/consumer; own L2 never stale).
__global__ void __launch_bounds__(256, 1) gru2(
    const void* __restrict__ x, const void* __restrict__ h0i,
    const void* __restrict__ Wxz, const void* __restrict__ Wxr, const void* __restrict__ Wxg,
    const void* __restrict__ Whz, const void* __restrict__ Whr, const void* __restrict__ Whg,
    const void* __restrict__ bhz, const void* __restrict__ bhr, const void* __restrict__ bhg,
    const void* __restrict__ WY, const void* __restrict__ bY,
    void* __restrict__ out, const int* __restrict__ flagp, int* __restrict__ barBase,
    const unsigned short* __restrict__ xb, const unsigned short* __restrict__ wcv,
    const unsigned short* __restrict__ wyc,
    float* __restrict__ h0f, float* __restrict__ h1f,
    float* __restrict__ z0f, float* __restrict__ z1f,
    unsigned short* __restrict__ h0b, unsigned short* __restrict__ h1b,
    unsigned short* __restrict__ rh0, unsigned short* __restrict__ rh1)
{
  extern __shared__ char smem[];
  unsigned short* sWP = (unsigned short*)smem;             // 65536 B
  unsigned short* sWQ = (unsigned short*)(smem + 65536);   // 65536 B
  floatx4* red = (floatx4*)(smem + 131072);                // 4096 B

  // counter regions (256 B lines)
  int* barCnt   = barBase;            // init barrier (8 lines)
  int* xcdArr   = barBase + 512;      // per-XCD arrival (8 lines)
  int* gTot     = barBase + 1024;     // single global line
  int* xcdGo    = barBase + 2048;     // per-XCD go flag (8 lines)
  int* xcdCount = barBase + 2560;     // per-XCD block census (8 lines)

  const int flag = *flagp;
  const int thr  = threadIdx.x;
  const int wave = thr >> 6;
  const int lane = thr & 63;
  const int l15  = lane & 15;
  const int kq   = (lane >> 4) * 8;
  const int blk  = blockIdx.x;
  const int role = blk >> 6;
  const int c0   = (blk & 63) * 16;
  // HW_REG_XCC_ID = hwreg 20, size 4
  const int myxcd = __builtin_amdgcn_s_getreg(20 | (3 << 11)) & 7;

  const unsigned short* xP  = flag ? xb                : (const unsigned short*)x;
  const unsigned short* Wzp = flag ? wcv + 0L*2097152  : (const unsigned short*)Wxz;
  const unsigned short* Wrp = flag ? wcv + 1L*2097152  : (const unsigned short*)Wxr;
  const unsigned short* Wgp = flag ? wcv + 2L*2097152  : (const unsigned short*)Wxg;
  const unsigned short* Uzp = flag ? wcv + 3L*2097152  : (const unsigned short*)Whz;
  const unsigned short* Urp = flag ? wcv + 4L*2097152  : (const unsigned short*)Whr;
  const unsigned short* Ugp = flag ? wcv + 5L*2097152  : (const unsigned short*)Whg;
  const unsigned short* WYp = flag ? wyc               : (const unsigned short*)WY;

  // ---- XCD census + leader election (old==0) ----
  int lead = 0;
  if (thr == 0) {
    int old = __hip_atomic_fetch_add(xcdCount + myxcd * 64, 1,
                                     __ATOMIC_RELAXED, __HIP_MEMORY_SCOPE_AGENT);
    lead = (old == 0);
  }

  // ---- one-time weight staging into LDS (block-local) ----
  {
    long off = (role >> 1) ? (long)HH : 0;
    const unsigned short* s0 = ((role & 1) ? Wrp : Wzp) + off;
    const unsigned short* s1 = ((role & 1) ? Urp : Uzp) + off;
    stage2(sWP, s0, s1, c0, thr);
  }
  if (blk < 128)      stage2(sWQ, Wgp + (blk >= 64 ? (long)HH : 0),
                             Ugp + (blk >= 64 ? (long)HH : 0), c0, thr);
  else if (blk < 192) stage1(sWQ, WYp, (blk - 128) * 16, thr);

  // ---- init hidden state (h_{-1}) into generation slot SL(-1)=SL(3) ----
  {
    int gtid = blk * 256 + thr;          // 0..65535
    int layer = gtid >> 15, i = gtid & 32767;
    float v = ldflag(h0i, (long)layer * NB + i, flag);
    unsigned int b = f2bf(v);
    if (layer == 0) { GSTW(h0f + SL(3) + i, v); GSTH(h0b + SL(3) + i, b); }
    else            { GSTW(h1f + SL(3) + i, v); GSTH(h1b + SL(3) + i, b); }
  }
  asm volatile("s_waitcnt vmcnt(0)" ::: "memory");
  gbar(barCnt, NBLK, blk);               // init barrier (full fences, proven)

  int xcdTot = 0;
  if (thr == 0)
    xcdTot = __hip_atomic_load(xcdCount + myxcd * 64, __ATOMIC_RELAXED, __HIP_MEMORY_SCOPE_AGENT);
  int pidx = 0;

  for (int s = 0; s < SEQ + 2; ++s) {
    const int sCur   = SL(s);        // slot for state produced this step
    const int sPrev  = SL(s - 1);    // h0 state of step s-1 / h1f write slot
    const int sPrev2 = SL(s - 2);    // h1 state of step s-2
    const int mt = wave & 1, khalf = wave >> 1;
    const int m = mt * 16 + l15;
    const int aoff = kq + khalf * 512;

    // ================= interval P =================
    {
      const int layer = role >> 1, zr = role & 1;
      const bool active = layer ? (s >= 1 && s <= SEQ) : (s < SEQ);
      if (active) {
        const unsigned short *a1, *a2;
        if (layer == 0) {
          a1 = xP + (long)m * (SEQ * HID) + (long)s * HID + aoff;
          a2 = h0b + sPrev + m * HID + aoff;
        } else {
          a1 = h0b + sPrev + m * HID + aoff;
          a2 = h1b + sPrev2 + m * HID + aoff;
        }
        floatx4 acc = gpair(a1, a2, sWP, khalf, lane);
        red[wave * 64 + lane] = acc;
        __syncthreads();
        if (wave < 2) {
          floatx4 ss = red[wave * 64 + lane] + red[(wave + 2) * 64 + lane];
          int n = c0 + l15;
          float bv = ldflag(zr ? bhr : bhz, (long)layer * HID + n, flag);
          #pragma unroll
          for (int r = 0; r < 4; ++r) {
            int row = wave * 16 + (lane >> 4) * 4 + r;
            int idx = row * HID + n;
            float v = sigmoidf_(ss[r] + bv);
            if (role == 0)      GSTW(z0f + idx, v);                       // single slot
            else if (role == 1) GSTH(rh0 + sCur + idx,
                                     (unsigned int)f2bf(v * h0f[sPrev + idx]));
            else if (role == 2) GSTW(z1f + sCur + idx, v);
            else                GSTH(rh1 + sCur + idx,
                                     (unsigned int)f2bf(v * h1f[sPrev2 + idx]));
          }
        }
      }
    }
    ++pidx; gbar8(xcdArr, gTot, xcdGo, myxcd, xcdTot, lead, pidx);

    // ================= interval Q =================
    if (role == 0) {            // g0 + h0 update (step s)
      if (s < SEQ) {
        const unsigned short* a1 = xP + (long)m * (SEQ * HID) + (long)s * HID + aoff;
        const unsigned short* a2 = rh0 + sCur + m * HID + aoff;
        floatx4 acc = gpair(a1, a2, sWQ, khalf, lane);
        red[wave * 64 + lane] = acc;
        __syncthreads();
        if (wave < 2) {
          floatx4 ss = red[wave * 64 + lane] + red[(wave + 2) * 64 + lane];
          int n = c0 + l15;
          float bv = ldflag(bhg, n, flag);
          #pragma unroll
          for (int r = 0; r < 4; ++r) {
            int row = wave * 16 + (lane >> 4) * 4 + r;
            int idx = row * HID + n;
            float g = tanhf(ss[r] + bv);
            float z = z0f[idx], hp = h0f[sPrev + idx];
            float hn = z * hp + (1.f - z) * g;
            GSTW(h0f + sCur + idx, hn);
            GSTH(h0b + sCur + idx, (unsigned int)f2bf(hn));
            if (s == SEQ - 1) outw_wt(out, flag, 16777216L + (long)row * 2048 + n, hn);
          }
        }
      }
    } else if (role == 1) {     // g1 + h1 update (step s-1)
      if (s >= 1 && s <= SEQ) {
        const unsigned short* a1 = h0b + sPrev + m * HID + aoff;
        const unsigned short* a2 = rh1 + sCur + m * HID + aoff;
        floatx4 acc = gpair(a1, a2, sWQ, khalf, lane);
        red[wave * 64 + lane] = acc;
        __syncthreads();
        if (wave < 2) {
          floatx4 ss = red[wave * 64 + lane] + red[(wave + 2) * 64 + lane];
          int n = c0 + l15;
          float bv = ldflag(bhg, (long)HID + n, flag);
          #pragma unroll
          for (int r = 0; r < 4; ++r) {
            int row = wave * 16 + (lane >> 4) * 4 + r;
            int idx = row * HID + n;
            float g = tanhf(ss[r] + bv);
            float z = z1f[sCur + idx], hp = h1f[sPrev2 + idx];
            float hn = z * hp + (1.f - z) * g;
            GSTW(h1f + sPrev + idx, hn);                       // h1 of step s-1
            GSTH(h1b + sPrev + idx, (unsigned int)f2bf(hn));
            if (s == SEQ) outw_wt(out, flag, 16777216L + (long)row * 2048 + 1024 + n, hn);
          }
        }
      }
    } else if (role == 2) {     // Y_{s-2}
      if (s >= 2) {
        const int cy = (blk - 128) * 16;
        const unsigned short* a = h1b + sPrev2 + m * HID + aoff;
        floatx4 acc = gsingle(a, sWQ, khalf, lane);
        red[wave * 64 + lane] = acc;
        __syncthreads();
        if (wave < 2) {
          floatx4 ss = red[wave * 64 + lane] + red[(wave + 2) * 64 + lane];
          int n = cy + l15;
          float bv = ldflag(bY, n, flag);
          const int tY = s - 2;
          #pragma unroll
          for (int r = 0; r < 4; ++r) {
            int brow = wave * 16 + (lane >> 4) * 4 + r;
            long oidx = ((long)brow * SEQ + tY) * HID + n;
            outw_wt(out, flag, oidx, ss[r] + bv);
          }
        }
      }
    }
    ++pidx; gbar8(xcdArr, gTot, xcdGo, myxcd, xcdTot, lead, pidx);
  }
}

extern "C" void kernel_launch(void* const* d_in, const int* in_sizes, int n_in,
                              void* d_out, int out_size, void* d_ws, size_t ws_size,
                              hipStream_t stream) {
  const void* x   = d_in[0];
  const void* h0i = d_in[1];
  const void* Wxz = d_in[2];
  const void* Wxr = d_in[3];
  const void* Wxg = d_in[4];
  const void* Whz = d_in[5];
  const void* Whr = d_in[6];
  const void* Whg = d_in[7];
  const void* bhz = d_in[8];
  const void* bhr = d_in[9];
  const void* bhg = d_in[10];
  const void* WY  = d_in[11];
  const void* bY  = d_in[12];

  char* ws = (char*)d_ws;
  int* flag    = (int*)ws;
  int* barBase = (int*)(ws + 1024);   // counter regions, 256 B lines
  // rotated state: R=4 slots each, except z0f (single-slot, block-local)
  float* z0f = (float*)(ws + 16384);                  // NB
  float* h0f = z0f + NB;                              // 4*NB
  float* h1f = h0f + 4 * NB;                          // 4*NB
  float* z1f = h1f + 4 * NB;                          // 4*NB
  unsigned short* h0b = (unsigned short*)(z1f + 4 * NB);  // 4*NB u16
  unsigned short* h1b = h0b + 4 * NB;
  unsigned short* rh0 = h1b + 4 * NB;
  unsigned short* rh1 = rh0 + 4 * NB;
  unsigned short* xb  = (unsigned short*)(ws + 3145728);  // ws + 3 MiB
  unsigned short* wcv = xb + 16777216L;
  unsigned short* wyc = wcv + 12582912L;

  hipMemsetAsync(barBase, 0, 12288, stream);
  detect_k<<<1, 64, 0, stream>>>((const unsigned int*)x, flag);
  convert_k<<<2048, 256, 0, stream>>>((const float*)x,
      (const float*)Wxz, (const float*)Wxr, (const float*)Wxg,
      (const float*)Whz, (const float*)Whr, (const float*)Whg,
      (const float*)WY, xb, wcv, wyc, flag);

  static int attr_set = 0;
  if (!attr_set) {
    hipFuncSetAttribute((const void*)gru2, hipFuncAttributeMaxDynamicSharedMemorySize, 135168);
    attr_set = 1;
  }

  void* out = d_out;
  const int* flagc = flag;
  int* barc = barBase;
  void* args[] = { (void*)&x, (void*)&h0i, (void*)&Wxz, (void*)&Wxr, (void*)&Wxg,
                   (void*)&Whz, (void*)&Whr, (void*)&Whg, (void*)&bhz, (void*)&bhr,
                   (void*)&bhg, (void*)&WY, (void*)&bY, (void*)&out, (void*)&flagc,
                   (void*)&barc, (void*)&xb, (void*)&wcv, (void*)&wyc,
                   (void*)&h0f, (void*)&h1f, (void*)&z0f, (void*)&z1f,
                   (void*)&h0b, (void*)&h1b, (void*)&rh0, (void*)&rh1 };
  hipLaunchCooperativeKernel((const void*)gru2, dim3(NBLK), dim3(256), args, 135168, stream);
}

// Round 9
// 7856.340 us; speedup vs baseline: 1.3638x; 1.0966x over previous
//
#include <hip/hip_runtime.h>
#include <hip/hip_bf16.h>

typedef __bf16 bf16x8 __attribute__((ext_vector_type(8)));
typedef float floatx4 __attribute__((ext_vector_type(4)));

#define HID 1024
#define HH (1024*1024)
#define SEQ 512
#define NB 32768  /* 32*1024 state elements */
#define NBLK 256
#define SL(k) ((((k) & 3)) * NB)   /* generation slot (element offset) */

__device__ __forceinline__ float bf2f(unsigned short u) {
  union { unsigned int i; float f; } v; v.i = ((unsigned int)u) << 16; return v.f;
}
__device__ __forceinline__ unsigned short f2bf(float f) {
  union { float f; unsigned int i; } v; v.f = f;
  unsigned int i = v.i;
  return (unsigned short)((i + 0x7fffu + ((i >> 16) & 1u)) >> 16);
}
__device__ __forceinline__ float ldflag(const void* p, long i, int flag) {
  return flag ? ((const float*)p)[i] : bf2f(((const unsigned short*)p)[i]);
}
__device__ __forceinline__ float sigmoidf_(float x) { return 1.0f / (1.0f + __expf(-x)); }

// plain stores (r3/r5/r7 proven path; release wbl2 at the barrier flushes them)
#define GSTH(p_, v_)   asm volatile("global_store_short %0, %1, off sc0 sc1" :: "v"(p_), "v"(v_) : "memory")
#define GSTW(p_, v_)   asm volatile("global_store_dword %0, %1, off sc0 sc1" :: "v"(p_), "v"(v_) : "memory")

__device__ __forceinline__ void outw_wt(void* out, int flag, long idx, float v) {
  if (flag) { GSTW((float*)out + idx, v); }
  else      { GSTH((unsigned short*)out + idx, (unsigned int)f2bf(v)); }
}

// ---- dtype detection: bf16 (flag=0) vs fp32 (flag=1) ----
__global__ void detect_k(const unsigned int* __restrict__ xw, int* __restrict__ flag) {
  unsigned int w = xw[threadIdx.x];
  int e = (w >> 7) & 0xFF;
  int ok = (e >= 100 && e <= 141) ? 1 : 0;
  unsigned long long m = __ballot(ok);
  if (threadIdx.x == 0) *flag = (__popcll(m) >= 36) ? 0 : 1;
}

// ---- fp32 -> bf16 conversion of x, 6 weight tensors, WY (no-op when flag=0) ----
__global__ void convert_k(const float* __restrict__ x,
                          const float* __restrict__ w0, const float* __restrict__ w1,
                          const float* __restrict__ w2, const float* __restrict__ w3,
                          const float* __restrict__ w4, const float* __restrict__ w5,
                          const float* __restrict__ wy,
                          unsigned short* __restrict__ xb, unsigned short* __restrict__ wc,
                          unsigned short* __restrict__ wyc, const int* __restrict__ flag) {
  if (*flag == 0) return;
  const float* Ws[6] = { w0, w1, w2, w3, w4, w5 };
  const long total = 3801088;
  for (long c = (long)blockIdx.x * 256 + threadIdx.x; c < total; c += (long)gridDim.x * 256) {
    long e = c * 8;
    const float* src; unsigned short* dst; long off;
    if (e < 16777216)      { src = x;  dst = xb;  off = e; }
    else if (e < 29360128) { long r = e - 16777216; int wi = (int)(r >> 21);
                             src = Ws[wi]; dst = wc + (long)wi * 2097152; off = r & 2097151; }
    else                   { src = wy; dst = wyc; off = e - 29360128; }
    float4 a = *(const float4*)(src + off);
    float4 b = *(const float4*)(src + off + 4);
    uint4 o;
    o.x = (unsigned)f2bf(a.x) | ((unsigned)f2bf(a.y) << 16);
    o.y = (unsigned)f2bf(a.z) | ((unsigned)f2bf(a.w) << 16);
    o.z = (unsigned)f2bf(b.x) | ((unsigned)f2bf(b.y) << 16);
    o.w = (unsigned)f2bf(b.z) | ((unsigned)f2bf(b.w) << 16);
    *(uint4*)(dst + off) = o;
  }
}

// ---- init-time grid barrier: round-3 proven (full fences per block) ----
__device__ __forceinline__ void gbar(int* cnt, int target, int blk) {
  __syncthreads();
  if (threadIdx.x == 0) {
    __builtin_amdgcn_fence(__ATOMIC_RELEASE, "agent");
    __hip_atomic_fetch_add(cnt + (blk & 7) * 64, 1, __ATOMIC_RELAXED, __HIP_MEMORY_SCOPE_AGENT);
    int ssum;
    do {
      ssum = 0;
      #pragma unroll
      for (int i = 0; i < 8; ++i)
        ssum += __hip_atomic_load(cnt + i * 64, __ATOMIC_RELAXED, __HIP_MEMORY_SCOPE_AGENT);
      if (ssum < target) __builtin_amdgcn_s_sleep(1);
    } while (ssum < target);
    __builtin_amdgcn_fence(__ATOMIC_ACQUIRE, "agent");
  }
  __syncthreads();
}

// ---- per-phase FLAT barrier (r9): no leader, no go-hop.
// Every thread0: early L1 buffer_inv (L1 is write-through - never dirty), then
// arrival RMW on its XCD line. LAST ARRIVER per XCD: release fence (wbl2 ->
// this XCD's dirty state reaches the coherent IF), plus - every 4th phase -
// the acquire fence (own-XCD L2+L1 inv) BEFORE posting, so any block that
// detects completion is guaranteed its XCD L2 was inv'd (same ordering
// guarantee as r8's leader scheme). Then posts the XCD count to its gTot
// line. ALL blocks poll the 8 gTot lines directly (r3-proven shape).
// Chain from last arrival: RMW + wbl2 + post-visible + detect = ~3 IF RTs
// (vs r8's 5: ...leader-detect + go-post + member-detect).
// Address rotation (R=4 slots, reuse distance 8 phases, inv gap <= 4 phases)
// covers all cross-phase L2 staleness, exactly as proven in r8.
__device__ __forceinline__ void gbar9(int* xcdArr, int* gTot,
                                      int myxcd, int xcdTot, int pidx) {
  asm volatile("s_waitcnt vmcnt(0)" ::: "memory");  // this wave's stores -> L2
  __syncthreads();                                  // all waves drained
  if (threadIdx.x == 0) {
    asm volatile("buffer_inv" ::: "memory");        // own-CU L1 inv, off-path
    int old = __hip_atomic_fetch_add(xcdArr + myxcd * 64, 1,
                                     __ATOMIC_RELAXED, __HIP_MEMORY_SCOPE_AGENT);
    if (old == pidx * xcdTot - 1) {                 // last arriver on this XCD
      __builtin_amdgcn_fence(__ATOMIC_RELEASE, "agent");    // wbl2 + wait
      if ((pidx & 3) == 0)
        __builtin_amdgcn_fence(__ATOMIC_ACQUIRE, "agent");  // own-XCD L2+L1 inv, 1-in-4
      __hip_atomic_fetch_add(gTot + myxcd * 64, xcdTot,
                             __ATOMIC_RELAXED, __HIP_MEMORY_SCOPE_AGENT);
    }
    const int target = NBLK * pidx;
    int ssum;
    do {
      ssum = 0;
      #pragma unroll
      for (int i = 0; i < 8; ++i)
        ssum += __hip_atomic_load(gTot + i * 64, __ATOMIC_RELAXED, __HIP_MEMORY_SCOPE_AGENT);
      if (ssum < target) __builtin_amdgcn_s_sleep(1);
    } while (ssum < target);
  }
  __syncthreads();
}

// ---- stage a (W,U) pair of 16 rows x K=1024 each into MFMA-frag-ordered LDS ----
// frag layout (ushort idx): ((m*32 + kc)*64 + L)*8, kc=k>>5, L=((k>>3)&3)*16 | row
__device__ __forceinline__ void stage2(unsigned short* dst,
                                       const unsigned short* __restrict__ s0,
                                       const unsigned short* __restrict__ s1,
                                       int n0, int tid) {
  const unsigned short* srcs[2] = { s0, s1 };
  #pragma unroll
  for (int i = 0; i < 16; ++i) {
    int idx = i * 256 + tid;          // 0..4095: 2 matrices x 16 rows x 128 k8
    int m = idx >> 11;
    int rem = idx & 2047;
    int r = rem >> 7, k8 = rem & 127;
    bf16x8 v = *(const bf16x8*)(srcs[m] + (long)(n0 + r) * HID + k8 * 8);
    int kc = k8 >> 2, L = ((k8 & 3) << 4) | r;
    *(bf16x8*)(dst + (((m * 32 + kc) * 64 + L) << 3)) = v;
  }
}
__device__ __forceinline__ void stage1(unsigned short* dst,
                                       const unsigned short* __restrict__ s0,
                                       int n0, int tid) {
  #pragma unroll
  for (int i = 0; i < 8; ++i) {
    int idx = i * 256 + tid;          // 0..2047
    int r = idx >> 7, k8 = idx & 127;
    bf16x8 v = *(const bf16x8*)(s0 + (long)(n0 + r) * HID + k8 * 8);
    int kc = k8 >> 2, L = ((k8 & 3) << 4) | r;
    *(bf16x8*)(dst + ((kc * 64 + L) << 3)) = v;
  }
}

// ---- per-wave GEMM: A from global (pre-offset), W from frag-ordered LDS ----
__device__ __forceinline__ floatx4 gpair(const unsigned short* __restrict__ a1,
                                         const unsigned short* __restrict__ a2,
                                         const unsigned short* sW, int khalf, int lane) {
  floatx4 acc = {0.f, 0.f, 0.f, 0.f};
  const unsigned short* w1 = sW + (((khalf * 16) * 64 + lane) << 3);
  const unsigned short* w2 = sW + (((32 + khalf * 16) * 64 + lane) << 3);
  #pragma unroll
  for (int j = 0; j < 16; ++j)
    acc = __builtin_amdgcn_mfma_f32_16x16x32_bf16(*(const bf16x8*)(a1 + j * 32),
                                                  *(const bf16x8*)(w1 + j * 512), acc, 0, 0, 0);
  #pragma unroll
  for (int j = 0; j < 16; ++j)
    acc = __builtin_amdgcn_mfma_f32_16x16x32_bf16(*(const bf16x8*)(a2 + j * 32),
                                                  *(const bf16x8*)(w2 + j * 512), acc, 0, 0, 0);
  return acc;
}
__device__ __forceinline__ floatx4 gsingle(const unsigned short* __restrict__ a,
                                           const unsigned short* sW, int khalf, int lane) {
  floatx4 acc = {0.f, 0.f, 0.f, 0.f};
  const unsigned short* w = sW + (((khalf * 16) * 64 + lane) << 3);
  #pragma unroll
  for (int j = 0; j < 16; ++j)
    acc = __builtin_amdgcn_mfma_f32_16x16x32_bf16(*(const bf16x8*)(a + j * 32),
                                                  *(const bf16x8*)(w + j * 512), acc, 0, 0, 0);
  return acc;
}

// Persistent GRU, 256 blocks x 256 threads, LDS-resident weights.
// P roles (blk>>6): 0=z0, 1=r0, 2=z1, 3=r1; 16 cols each ((blk&63)*16).
// Q roles: 0=g0, 1=g1, 2=Y (16 cols, (blk-128)*16), 3=idle.
// State rotation (R=4 step slots): h0b,h1b,rh0,rh1,z1f,h0f,h1f. z0f single-slot
// (same-block producer/consumer; own L2 never stale).
__global__ void __launch_bounds__(256, 1) gru2(
    const void* __restrict__ x, const void* __restrict__ h0i,
    const void* __restrict__ Wxz, const void* __restrict__ Wxr, const void* __restrict__ Wxg,
    const void* __restrict__ Whz, const void* __restrict__ Whr, const void* __restrict__ Whg,
    const void* __restrict__ bhz, const void* __restrict__ bhr, const void* __restrict__ bhg,
    const void* __restrict__ WY, const void* __restrict__ bY,
    void* __restrict__ out, const int* __restrict__ flagp, int* __restrict__ barBase,
    const unsigned short* __restrict__ xb, const unsigned short* __restrict__ wcv,
    const unsigned short* __restrict__ wyc,
    float* __restrict__ h0f, float* __restrict__ h1f,
    float* __restrict__ z0f, float* __restrict__ z1f,
    unsigned short* __restrict__ h0b, unsigned short* __restrict__ h1b,
    unsigned short* __restrict__ rh0, unsigned short* __restrict__ rh1)
{
  extern __shared__ char smem[];
  unsigned short* sWP = (unsigned short*)smem;             // 65536 B
  unsigned short* sWQ = (unsigned short*)(smem + 65536);   // 65536 B
  floatx4* red = (floatx4*)(smem + 131072);                // 4096 B

  // counter regions (256 B lines)
  int* barCnt   = barBase;            // init barrier (8 lines)
  int* xcdArr   = barBase + 512;      // per-XCD arrival (8 lines)
  int* gTot     = barBase + 1024;     // global, one line per XCD (8 lines)
  int* xcdCount = barBase + 2560;     // per-XCD block census (8 lines)

  const int flag = *flagp;
  const int thr  = threadIdx.x;
  const int wave = thr >> 6;
  const int lane = thr & 63;
  const int l15  = lane & 15;
  const int kq   = (lane >> 4) * 8;
  const int blk  = blockIdx.x;
  const int role = blk >> 6;
  const int c0   = (blk & 63) * 16;
  // HW_REG_XCC_ID = hwreg 20, size 4
  const int myxcd = __builtin_amdgcn_s_getreg(20 | (3 << 11)) & 7;

  const unsigned short* xP  = flag ? xb                : (const unsigned short*)x;
  const unsigned short* Wzp = flag ? wcv + 0L*2097152  : (const unsigned short*)Wxz;
  const unsigned short* Wrp = flag ? wcv + 1L*2097152  : (const unsigned short*)Wxr;
  const unsigned short* Wgp = flag ? wcv + 2L*2097152  : (const unsigned short*)Wxg;
  const unsigned short* Uzp = flag ? wcv + 3L*2097152  : (const unsigned short*)Whz;
  const unsigned short* Urp = flag ? wcv + 4L*2097152  : (const unsigned short*)Whr;
  const unsigned short* Ugp = flag ? wcv + 5L*2097152  : (const unsigned short*)Whg;
  const unsigned short* WYp = flag ? wyc               : (const unsigned short*)WY;

  // ---- XCD census ----
  if (thr == 0)
    __hip_atomic_fetch_add(xcdCount + myxcd * 64, 1,
                           __ATOMIC_RELAXED, __HIP_MEMORY_SCOPE_AGENT);

  // ---- one-time weight staging into LDS (block-local) ----
  {
    long off = (role >> 1) ? (long)HH : 0;
    const unsigned short* s0 = ((role & 1) ? Wrp : Wzp) + off;
    const unsigned short* s1 = ((role & 1) ? Urp : Uzp) + off;
    stage2(sWP, s0, s1, c0, thr);
  }
  if (blk < 128)      stage2(sWQ, Wgp + (blk >= 64 ? (long)HH : 0),
                             Ugp + (blk >= 64 ? (long)HH : 0), c0, thr);
  else if (blk < 192) stage1(sWQ, WYp, (blk - 128) * 16, thr);

  // ---- init hidden state (h_{-1}) into generation slot SL(-1)=SL(3) ----
  {
    int gtid = blk * 256 + thr;          // 0..65535
    int layer = gtid >> 15, i = gtid & 32767;
    float v = ldflag(h0i, (long)layer * NB + i, flag);
    unsigned int b = f2bf(v);
    if (layer == 0) { GSTW(h0f + SL(3) + i, v); GSTH(h0b + SL(3) + i, b); }
    else            { GSTW(h1f + SL(3) + i, v); GSTH(h1b + SL(3) + i, b); }
  }
  asm volatile("s_waitcnt vmcnt(0)" ::: "memory");
  gbar(barCnt, NBLK, blk);               // init barrier (full fences, proven)

  int xcdTot = 0;
  if (thr == 0)
    xcdTot = __hip_atomic_load(xcdCount + myxcd * 64, __ATOMIC_RELAXED, __HIP_MEMORY_SCOPE_AGENT);
  int pidx = 0;

  for (int s = 0; s < SEQ + 2; ++s) {
    const int sCur   = SL(s);        // slot for state produced this step
    const int sPrev  = SL(s - 1);    // h0 state of step s-1 / h1f write slot
    const int sPrev2 = SL(s - 2);    // h1 state of step s-2
    const int mt = wave & 1, khalf = wave >> 1;
    const int m = mt * 16 + l15;
    const int aoff = kq + khalf * 512;

    // ================= interval P =================
    {
      const int layer = role >> 1, zr = role & 1;
      const bool active = layer ? (s >= 1 && s <= SEQ) : (s < SEQ);
      if (active) {
        const unsigned short *a1, *a2;
        if (layer == 0) {
          a1 = xP + (long)m * (SEQ * HID) + (long)s * HID + aoff;
          a2 = h0b + sPrev + m * HID + aoff;
        } else {
          a1 = h0b + sPrev + m * HID + aoff;
          a2 = h1b + sPrev2 + m * HID + aoff;
        }
        floatx4 acc = gpair(a1, a2, sWP, khalf, lane);
        red[wave * 64 + lane] = acc;
        __syncthreads();
        if (wave < 2) {
          floatx4 ss = red[wave * 64 + lane] + red[(wave + 2) * 64 + lane];
          int n = c0 + l15;
          float bv = ldflag(zr ? bhr : bhz, (long)layer * HID + n, flag);
          #pragma unroll
          for (int r = 0; r < 4; ++r) {
            int row = wave * 16 + (lane >> 4) * 4 + r;
            int idx = row * HID + n;
            float v = sigmoidf_(ss[r] + bv);
            if (role == 0)      GSTW(z0f + idx, v);                       // single slot
            else if (role == 1) GSTH(rh0 + sCur + idx,
                                     (unsigned int)f2bf(v * h0f[sPrev + idx]));
            else if (role == 2) GSTW(z1f + sCur + idx, v);
            else                GSTH(rh1 + sCur + idx,
                                     (unsigned int)f2bf(v * h1f[sPrev2 + idx]));
          }
        }
      }
    }
    ++pidx; gbar9(xcdArr, gTot, myxcd, xcdTot, pidx);

    // ================= interval Q =================
    if (role == 0) {            // g0 + h0 update (step s)
      if (s < SEQ) {
        const unsigned short* a1 = xP + (long)m * (SEQ * HID) + (long)s * HID + aoff;
        const unsigned short* a2 = rh0 + sCur + m * HID + aoff;
        floatx4 acc = gpair(a1, a2, sWQ, khalf, lane);
        red[wave * 64 + lane] = acc;
        __syncthreads();
        if (wave < 2) {
          floatx4 ss = red[wave * 64 + lane] + red[(wave + 2) * 64 + lane];
          int n = c0 + l15;
          float bv = ldflag(bhg, n, flag);
          #pragma unroll
          for (int r = 0; r < 4; ++r) {
            int row = wave * 16 + (lane >> 4) * 4 + r;
            int idx = row * HID + n;
            float g = tanhf(ss[r] + bv);
            float z = z0f[idx], hp = h0f[sPrev + idx];
            float hn = z * hp + (1.f - z) * g;
            GSTW(h0f + sCur + idx, hn);
            GSTH(h0b + sCur + idx, (unsigned int)f2bf(hn));
            if (s == SEQ - 1) outw_wt(out, flag, 16777216L + (long)row * 2048 + n, hn);
          }
        }
      }
    } else if (role == 1) {     // g1 + h1 update (step s-1)
      if (s >= 1 && s <= SEQ) {
        const unsigned short* a1 = h0b + sPrev + m * HID + aoff;
        const unsigned short* a2 = rh1 + sCur + m * HID + aoff;
        floatx4 acc = gpair(a1, a2, sWQ, khalf, lane);
        red[wave * 64 + lane] = acc;
        __syncthreads();
        if (wave < 2) {
          floatx4 ss = red[wave * 64 + lane] + red[(wave + 2) * 64 + lane];
          int n = c0 + l15;
          float bv = ldflag(bhg, (long)HID + n, flag);
          #pragma unroll
          for (int r = 0; r < 4; ++r) {
            int row = wave * 16 + (lane >> 4) * 4 + r;
            int idx = row * HID + n;
            float g = tanhf(ss[r] + bv);
            float z = z1f[sCur + idx], hp = h1f[sPrev2 + idx];
            float hn = z * hp + (1.f - z) * g;
            GSTW(h1f + sPrev + idx, hn);                       // h1 of step s-1
            GSTH(h1b + sPrev + idx, (unsigned int)f2bf(hn));
            if (s == SEQ) outw_wt(out, flag, 16777216L + (long)row * 2048 + 1024 + n, hn);
          }
        }
      }
    } else if (role == 2) {     // Y_{s-2}
      if (s >= 2) {
        const int cy = (blk - 128) * 16;
        const unsigned short* a = h1b + sPrev2 + m * HID + aoff;
        floatx4 acc = gsingle(a, sWQ, khalf, lane);
        red[wave * 64 + lane] = acc;
        __syncthreads();
        if (wave < 2) {
          floatx4 ss = red[wave * 64 + lane] + red[(wave + 2) * 64 + lane];
          int n = cy + l15;
          float bv = ldflag(bY, n, flag);
          const int tY = s - 2;
          #pragma unroll
          for (int r = 0; r < 4; ++r) {
            int brow = wave * 16 + (lane >> 4) * 4 + r;
            long oidx = ((long)brow * SEQ + tY) * HID + n;
            outw_wt(out, flag, oidx, ss[r] + bv);
          }
        }
      }
    }
    ++pidx; gbar9(xcdArr, gTot, myxcd, xcdTot, pidx);
  }
}

extern "C" void kernel_launch(void* const* d_in, const int* in_sizes, int n_in,
                              void* d_out, int out_size, void* d_ws, size_t ws_size,
                              hipStream_t stream) {
  const void* x   = d_in[0];
  const void* h0i = d_in[1];
  const void* Wxz = d_in[2];
  const void* Wxr = d_in[3];
  const void* Wxg = d_in[4];
  const void* Whz = d_in[5];
  const void* Whr = d_in[6];
  const void* Whg = d_in[7];
  const void* bhz = d_in[8];
  const void* bhr = d_in[9];
  const void* bhg = d_in[10];
  const void* WY  = d_in[11];
  const void* bY  = d_in[12];

  char* ws = (char*)d_ws;
  int* flag    = (int*)ws;
  int* barBase = (int*)(ws + 1024);   // counter regions, 256 B lines
  // rotated state: R=4 slots each, except z0f (single-slot, block-local)
  float* z0f = (float*)(ws + 16384);                  // NB
  float* h0f = z0f + NB;                              // 4*NB
  float* h1f = h0f + 4 * NB;                          // 4*NB
  float* z1f = h1f + 4 * NB;                          // 4*NB
  unsigned short* h0b = (unsigned short*)(z1f + 4 * NB);  // 4*NB u16
  unsigned short* h1b = h0b + 4 * NB;
  unsigned short* rh0 = h1b + 4 * NB;
  unsigned short* rh1 = rh0 + 4 * NB;
  unsigned short* xb  = (unsigned short*)(ws + 3145728);  // ws + 3 MiB
  unsigned short* wcv = xb + 16777216L;
  unsigned short* wyc = wcv + 12582912L;

  hipMemsetAsync(barBase, 0, 12288, stream);
  detect_k<<<1, 64, 0, stream>>>((const unsigned int*)x, flag);
  convert_k<<<2048, 256, 0, stream>>>((const float*)x,
      (const float*)Wxz, (const float*)Wxr, (const float*)Wxg,
      (const float*)Whz, (const float*)Whr, (const float*)Whg,
      (const float*)WY, xb, wcv, wyc, flag);

  static int attr_set = 0;
  if (!attr_set) {
    hipFuncSetAttribute((const void*)gru2, hipFuncAttributeMaxDynamicSharedMemorySize, 135168);
    attr_set = 1;
  }

  void* out = d_out;
  const int* flagc = flag;
  int* barc = barBase;
  void* args[] = { (void*)&x, (void*)&h0i, (void*)&Wxz, (void*)&Wxr, (void*)&Wxg,
                   (void*)&Whz, (void*)&Whr, (void*)&Whg, (void*)&bhz, (void*)&bhr,
                   (void*)&bhg, (void*)&WY, (void*)&bY, (void*)&out, (void*)&flagc,
                   (void*)&barc, (void*)&xb, (void*)&wcv, (void*)&wyc,
                   (void*)&h0f, (void*)&h1f, (void*)&z0f, (void*)&z1f,
                   (void*)&h0b, (void*)&h1b, (void*)&rh0, (void*)&rh1 };
  hipLaunchCooperativeKernel((const void*)gru2, dim3(NBLK), dim3(256), args, 135168, stream);
}